// Round 11
// baseline (108.012 us; speedup 1.0000x reference)
//
#include <hip/hip_runtime.h>
#include <math.h>

#define PROJ 8192
#define NB   16
#define NC   512
#define HW   196      // 14*14
#define KP   224      // K padded (7 chunks of 32)
#define LST  40       // LDS row stride in bf16 elems (80 B)
#define XELE ((size_t)NB * NC * KP)

typedef __attribute__((ext_vector_type(8))) short bf16x8;   // 16 B MFMA frag
typedef __attribute__((ext_vector_type(4))) short short4v;
typedef __attribute__((ext_vector_type(4))) float f32x4;

__device__ __forceinline__ unsigned bf16_rne(float f) {
    unsigned u = __builtin_bit_cast(unsigned, f);
    return (u + 0x7fffu + ((u >> 16) & 1u)) >> 16;
}

// ---------------------------------------------------------------------------
// Kernel 0 (prep): x fp32 -> xh/xl bf16 [8192 x 224], K zero-padded.
// XCD-PINNED: block e+8t handles batch pair (2e, 2e+1) => the same XCD's L2
// that gram (blk&7 == e) will read from. grid = 1792 = 8 xcd * 224.
// ---------------------------------------------------------------------------
__global__ __launch_bounds__(256)
void cbp_prep(const float* __restrict__ x,
              short* __restrict__ xh, short* __restrict__ xl) {
    const int e    = blockIdx.x & 7;            // xcd / batch pair
    const int t    = blockIdx.x >> 3;           // 0..223
    const int task = t * 256 + threadIdx.x;     // 0..57343 within pair
    const int q    = task % 56;
    const int rp   = task / 56;                 // row in pair 0..1023
    const int row  = e * 1024 + rp;             // global row
    float4 v = {0.f, 0.f, 0.f, 0.f};
    if (q < 49) v = *(const float4*)&x[(size_t)row * HW + 4 * q];
    const float f[4] = {v.x, v.y, v.z, v.w};
    short4v h, l;
#pragma unroll
    for (int c = 0; c < 4; ++c) {
        const unsigned hb = bf16_rne(f[c]);
        h[c] = (short)hb;
        l[c] = (short)bf16_rne(f[c] - __builtin_bit_cast(float, hb << 16));
    }
    *(short4v*)&xh[(size_t)row * KP + 4 * q] = h;
    *(short4v*)&xl[(size_t)row * KP + 4 * q] = l;
}

// ---------------------------------------------------------------------------
// Kernel 1 (gram): 512 blocks x 256 thr (4 waves), tile 128(rows)x64(cols),
// 64.5 KB LDS -> TRUE 2 blocks/CU with independent barrier phases.
// blk = xcd | (tile<<3) | (hi<<8); b = 2*xcd + hi (matches prep's pin).
// Wave w owns a 32x64 sub-tile (acc 2x4). LDS staging is a pure bf16 copy,
// VGPR-prefetched one chunk ahead. Scatter into private 32KB sketch.
// ---------------------------------------------------------------------------
__global__ __launch_bounds__(256)
void cbp_gram(const short* __restrict__ xh, const short* __restrict__ xl,
              const float* __restrict__ s1, const float* __restrict__ s2,
              const int*   __restrict__ h1, const int*   __restrict__ h2,
              float* __restrict__ partials) {
    __shared__ float sk[PROJ];          // 32 KB
    __shared__ short Ah[128 * LST];     // 10 KB each
    __shared__ short Al[128 * LST];
    __shared__ short Bh[64 * LST];      // 5 KB each
    __shared__ short Bl[64 * LST];
    __shared__ int   lh1[128], lh2[64];
    __shared__ float ls1[128], ls2[64];

    const int tid = threadIdx.x;
    const int blk = blockIdx.x;
    const int xcd = blk & 7;
    const int tj  = (blk >> 3) & 31;
    const int hi  = blk >> 8;
    const int b   = 2 * xcd + hi;
    const int I   = tj >> 3, J = tj & 7;
    const int c1base = I * 128, c2base = J * 64;

    for (int i = tid; i < PROJ; i += 256) sk[i] = 0.f;
    if (tid < 128) {
        lh1[tid] = h1[c1base + tid];  ls1[tid] = s1[c1base + tid];
    } else {
        const int t = tid - 128;
        if (t < 64) { lh2[t] = h2[c2base + t];  ls2[t] = s2[c2base + t]; }
    }

    const int wave = tid >> 6, lane = tid & 63;
    const int quad = lane >> 4, l15 = lane & 15;
    const int wr = wave * 32;           // 32x64 sub-tile per wave

    // Staging tasks: A = 512 slots (2/thread), B = 256 slots (1/thread).
    const int arow0 = tid >> 2,  aslot0 = tid & 3;           // A task 0
    const int arow1 = (256 + tid) >> 2, aslot1 = tid & 3;    // A task 1 (rows 64..127)
    const int brow  = tid >> 2,  bslot = tid & 3;            // B task (rows 0..63)

    const size_t bA0 = ((size_t)b * NC + c1base + arow0) * KP + aslot0 * 8;
    const size_t bA1 = ((size_t)b * NC + c1base + arow1) * KP + aslot1 * 8;
    const size_t bB  = ((size_t)b * NC + c2base + brow ) * KP + bslot  * 8;

    bf16x8 pa0h, pa0l, pa1h, pa1l, pbh, pbl;
    pa0h = *(const bf16x8*)&xh[bA0];  pa0l = *(const bf16x8*)&xl[bA0];
    pa1h = *(const bf16x8*)&xh[bA1];  pa1l = *(const bf16x8*)&xl[bA1];
    pbh  = *(const bf16x8*)&xh[bB];   pbl  = *(const bf16x8*)&xl[bB];

    f32x4 acc[2][4];
#pragma unroll
    for (int i = 0; i < 2; ++i)
#pragma unroll
        for (int j = 0; j < 4; ++j) acc[i][j] = (f32x4){0.f, 0.f, 0.f, 0.f};

    for (int kc = 0; kc < 7; ++kc) {
        __syncthreads();                // LDS consumed (covers h/s on kc==0)
        *(bf16x8*)&Ah[arow0 * LST + aslot0 * 8] = pa0h;
        *(bf16x8*)&Al[arow0 * LST + aslot0 * 8] = pa0l;
        *(bf16x8*)&Ah[arow1 * LST + aslot1 * 8] = pa1h;
        *(bf16x8*)&Al[arow1 * LST + aslot1 * 8] = pa1l;
        *(bf16x8*)&Bh[brow * LST + bslot * 8]   = pbh;
        *(bf16x8*)&Bl[brow * LST + bslot * 8]   = pbl;
        if (kc < 6) {
            const size_t off = (size_t)(kc + 1) * 32;
            pa0h = *(const bf16x8*)&xh[bA0 + off];  pa0l = *(const bf16x8*)&xl[bA0 + off];
            pa1h = *(const bf16x8*)&xh[bA1 + off];  pa1l = *(const bf16x8*)&xl[bA1 + off];
            pbh  = *(const bf16x8*)&xh[bB  + off];  pbl  = *(const bf16x8*)&xl[bB  + off];
        }
        __syncthreads();

        bf16x8 ahf[2], alf[2], bhf[4], blf[4];
#pragma unroll
        for (int i = 0; i < 2; ++i) {
            const int ra = wr + i * 16 + l15;
            ahf[i] = *(const bf16x8*)&Ah[ra * LST + quad * 8];
            alf[i] = *(const bf16x8*)&Al[ra * LST + quad * 8];
        }
#pragma unroll
        for (int j = 0; j < 4; ++j) {
            const int rb = j * 16 + l15;
            bhf[j] = *(const bf16x8*)&Bh[rb * LST + quad * 8];
            blf[j] = *(const bf16x8*)&Bl[rb * LST + quad * 8];
        }
#pragma unroll
        for (int i = 0; i < 2; ++i)
#pragma unroll
            for (int j = 0; j < 4; ++j) {
                acc[i][j] = __builtin_amdgcn_mfma_f32_16x16x32_bf16(ahf[i], bhf[j], acc[i][j], 0, 0, 0);
                acc[i][j] = __builtin_amdgcn_mfma_f32_16x16x32_bf16(ahf[i], blf[j], acc[i][j], 0, 0, 0);
                acc[i][j] = __builtin_amdgcn_mfma_f32_16x16x32_bf16(alf[i], bhf[j], acc[i][j], 0, 0, 0);
            }
    }

    // Preload scatter coefficients into registers, then scatter.
    int   ha[8], hb[4];
    float sa[8], sb[4];
#pragma unroll
    for (int i = 0; i < 2; ++i)
#pragma unroll
        for (int rg = 0; rg < 4; ++rg) {
            const int r = wr + i * 16 + quad * 4 + rg;
            ha[i * 4 + rg] = lh1[r];  sa[i * 4 + rg] = ls1[r];
        }
#pragma unroll
    for (int j = 0; j < 4; ++j) {
        const int c = j * 16 + l15;
        hb[j] = lh2[c];  sb[j] = ls2[c];
    }
#pragma unroll
    for (int i = 0; i < 2; ++i)
#pragma unroll
        for (int j = 0; j < 4; ++j)
#pragma unroll
            for (int rg = 0; rg < 4; ++rg) {
                const int bin = (ha[i * 4 + rg] + hb[j]) & (PROJ - 1);
                atomicAdd(&sk[bin], sa[i * 4 + rg] * sb[j] * acc[i][j][rg]);
            }
    __syncthreads();

    float4* dst = (float4*)(partials + (size_t)blk * PROJ);
    const float4* src = (const float4*)sk;
    for (int i = tid; i < PROJ / 4; i += 256) dst[i] = src[i];
}

// ---------------------------------------------------------------------------
// Kernel 2 (reduce): sum 32 partials/bin (XCD-local) + signed sqrt + ssq.
// grid = 512: blk = xcd | (k<<3), k = hi*32+seg, b = 2*xcd+hi.
// ---------------------------------------------------------------------------
__global__ __launch_bounds__(256)
void cbp_reduce(const float* __restrict__ partials, float* __restrict__ y,
                float* __restrict__ ssqp) {
    const int blk = blockIdx.x;
    const int xcd = blk & 7;
    const int k   = blk >> 3;
    const int hi  = k >> 5;
    const int seg = k & 31;
    const int b   = 2 * xcd + hi;
    const int tid = threadIdx.x;
    const int bin = seg * 256 + tid;

    float s = 0.f;
#pragma unroll
    for (int u = 0; u < 32; ++u) {
        const int u2 = (u + seg) & 31;                  // rotate partial order
        const int pb = xcd | (u2 << 3) | (hi << 8);     // gram blk of (b, tile=u2)
        s += partials[(size_t)pb * PROJ + bin];
    }

    const float m = sqrtf(fabsf(s) + 1e-8f);
    const float o = (s > 0.f) ? m : (s < 0.f ? -m : 0.f);   // sign(0)=0
    y[b * PROJ + bin] = o;

    __shared__ float red[256];
    red[tid] = o * o;
    __syncthreads();
#pragma unroll
    for (int st = 128; st >= 1; st >>= 1) {
        if (tid < st) red[tid] += red[tid + st];
        __syncthreads();
    }
    if (tid == 0) ssqp[blk] = red[0];
}

// ---------------------------------------------------------------------------
// Kernel 3 (norm): y_b /= max(||y_b||, 1e-12). grid = 32 (b, half-row).
// ---------------------------------------------------------------------------
__global__ __launch_bounds__(256)
void cbp_normalize(float* __restrict__ y, const float* __restrict__ ssqp) {
    const int b   = blockIdx.x >> 1;
    const int off = (blockIdx.x & 1) * 4096;
    const int tid = threadIdx.x;
    float ssq = 0.f;
#pragma unroll
    for (int seg = 0; seg < 32; ++seg)
        ssq += ssqp[(b >> 1) | (((b & 1) * 32 + seg) << 3)];
    const float inv = 1.0f / fmaxf(sqrtf(ssq), 1e-12f);

    float4* row = (float4*)&y[(size_t)b * PROJ + off];
#pragma unroll
    for (int j = 0; j < 4; ++j) {
        float4 v = row[j * 256 + tid];
        v.x *= inv; v.y *= inv; v.z *= inv; v.w *= inv;
        row[j * 256 + tid] = v;
    }
}

// ---------------------------------------------------------------------------
extern "C" void kernel_launch(void* const* d_in, const int* in_sizes, int n_in,
                              void* d_out, int out_size, void* d_ws, size_t ws_size,
                              hipStream_t stream) {
    const float* x  = (const float*)d_in[0];
    const float* s1 = (const float*)d_in[1];
    const float* s2 = (const float*)d_in[2];
    const int*   h1 = (const int*)d_in[3];
    const int*   h2 = (const int*)d_in[4];
    float* y = (float*)d_out;                    // [16, 8192]

    // ws layout (~24.2 MB used):
    short* xh = (short*)d_ws;                    // 3.67 MB
    short* xl = xh + XELE;                       // 3.67 MB
    float* partials = (float*)(xl + XELE);       // 512 * 32 KB = 16.8 MB
    float* ssqp = partials + (size_t)512 * PROJ; // 512 floats

    hipLaunchKernelGGL(cbp_prep, dim3(1792), dim3(256), 0, stream, x, xh, xl);
    hipLaunchKernelGGL(cbp_gram, dim3(512), dim3(256), 0, stream,
                       xh, xl, s1, s2, h1, h2, partials);
    hipLaunchKernelGGL(cbp_reduce, dim3(512), dim3(256), 0, stream,
                       partials, y, ssqp);
    hipLaunchKernelGGL(cbp_normalize, dim3(32), dim3(256), 0, stream, y, ssqp);
}